// Round 9
// baseline (217.101 us; speedup 1.0000x reference)
//
#include <hip/hip_runtime.h>
#include <hip/hip_bf16.h>
#include <cstddef>

// ---------------------------------------------------------------------------
// AttentionBlock: B=2, H=W=64 (S=4096), C=512, GROUPS=32, fp32 in/out.
// GroupNorm -> qkv -> P = softmax(q k^T / sqrt(C)) -> o = P v -> o@Wp + bp + x
// R9: algebraic fusion, no barriers (R7/R8 proved software grid sync costs
//     30-140us/barrier on 8 XCDs -- direction abandoned).
//       o@Wp = (P/l . v)@Wp = P/l . (v@Wp)
//     vpT = Wp^T v^T is itself a B^T-GEMM on existing buffers (A=WpT,
//     Bt=v rows of qkv) producing exactly the transposed layout PV needs:
//     replaces the vtrans transpose AND the out-proj GEMM AND o2's 32MB
//     round-trip AND one graph node. PV epilogue: acc/l + bp + x -> fp32 out.
//     5 nodes: prep | gn | qkv | qk+vpT | pv.
// ---------------------------------------------------------------------------

typedef __bf16 bf16;
typedef __attribute__((ext_vector_type(8))) __bf16 bf16x8;
typedef __attribute__((ext_vector_type(4))) __bf16 bf16x4;
typedef __attribute__((ext_vector_type(4))) float f32x4;

#define SEQ   4096
#define CCH   512
#define NBAT  2
#define SMEM_BYTES 32768   // As 16K + Bs up to 16K; EPI2 reduce reuses As

// ---------------------------------------------------------------------------
// prep unit: bid<512 GN-stats partials (statsP[bg*16+c]=S, +8+c=SS, race-free)
//            bid in [512,1536) weight transpose-cast; bid==1536 bias pack.
__device__ __forceinline__ void prep_unit(
    char* smem, int bid, const float* __restrict__ x,
    const float* __restrict__ Wq, const float* __restrict__ Wk,
    const float* __restrict__ Wv, const float* __restrict__ Wp,
    const float* __restrict__ bq, const float* __restrict__ bk,
    const float* __restrict__ bv,
    float* __restrict__ statsP, bf16* __restrict__ WqkvT,
    bf16* __restrict__ WpT, float* __restrict__ biasQKV) {
    const int tid = threadIdx.x;
    if (bid < 512) {
        float* red = (float*)smem;            // 8 floats
        int bg = bid >> 3, c = bid & 7;
        int b = bg >> 5, g = bg & 31;
        const float* base = x + (size_t)b * SEQ * CCH + g * 16;
        float s = 0.f, ss = 0.f;
        for (int i = tid; i < 2048; i += 256) {      // 512 spatial x 4 float4
            int sp = c * 512 + (i >> 2), q = i & 3;
            float4 v = *(const float4*)(base + (size_t)sp * CCH + q * 4);
            s  += v.x + v.y + v.z + v.w;
            ss += v.x * v.x + v.y * v.y + v.z * v.z + v.w * v.w;
        }
        #pragma unroll
        for (int o = 32; o > 0; o >>= 1) { s += __shfl_down(s, o); ss += __shfl_down(ss, o); }
        int wave = tid >> 6, lane = tid & 63;
        if (lane == 0) { red[wave] = s; red[4 + wave] = ss; }
        __syncthreads();
        if (tid == 0) {
            statsP[bg * 16 + c]     = red[0] + red[1] + red[2] + red[3];
            statsP[bg * 16 + 8 + c] = red[4] + red[5] + red[6] + red[7];
        }
        __syncthreads();
    } else if (bid < 1536) {
        float (*tile)[33] = (float(*)[33])smem;      // 4224 B
        int w = bid - 512;
        int z = w >> 8, rest = w & 255;
        int k0 = (rest >> 4) * 32, n0 = (rest & 15) * 32;
        const float* W = (z == 0) ? Wq : (z == 1) ? Wk : (z == 2) ? Wv : Wp;
        int tx = tid & 31, ty = tid >> 5;
        #pragma unroll
        for (int i = ty; i < 32; i += 8)
            tile[i][tx] = W[(size_t)(k0 + i) * CCH + n0 + tx];
        __syncthreads();
        bf16* dst = (z < 3) ? (WqkvT + (size_t)z * CCH * CCH) : WpT;
        #pragma unroll
        for (int i = ty; i < 32; i += 8)
            dst[(size_t)(n0 + i) * CCH + k0 + tx] = (bf16)tile[tx][i];
        __syncthreads();
    } else {
        for (int i = tid; i < 1536; i += 256) {
            float v = (i < 512) ? bq[i] : (i < 1024) ? bk[i - 512] : bv[i - 1024];
            biasQKV[i] = v;
        }
    }
}

__global__ __launch_bounds__(256) void k_prep(
    const float* x, const float* Wq, const float* Wk, const float* Wv,
    const float* Wp, const float* bq, const float* bk, const float* bv,
    float* statsP, bf16* WqkvT, bf16* WpT, float* biasQKV) {
    __shared__ __align__(16) char smem[4352];
    prep_unit(smem, blockIdx.x, x, Wq, Wk, Wv, Wp, bq, bk, bv,
              statsP, WqkvT, WpT, biasQKV);
}

// Normalize + affine + cast; per-block (mu, rstd) table from partials.
__global__ __launch_bounds__(256) void k_gn(
    const float* __restrict__ x, const float* __restrict__ statsP,
    const float* __restrict__ gamma, const float* __restrict__ beta,
    bf16* __restrict__ xn) {
    __shared__ float tbl[128];
    const int tid = threadIdx.x;
    if (tid < 64) {
        float S = 0.f, SS = 0.f;
        #pragma unroll
        for (int c = 0; c < 8; ++c) { S += statsP[tid * 16 + c]; SS += statsP[tid * 16 + 8 + c]; }
        float mu = S * (1.f / 65536.f);
        float rs = rsqrtf(SS * (1.f / 65536.f) - mu * mu + 1e-5f);
        tbl[tid * 2] = mu; tbl[tid * 2 + 1] = rs;
    }
    __syncthreads();
    size_t idx = (size_t)blockIdx.x * 256 + tid;
    int c4 = (int)(idx & 127);
    int b = (int)(idx >> 19);
    int bg = b * 32 + (c4 >> 2);
    float mu = tbl[bg * 2], rs = tbl[bg * 2 + 1];
    float4 v  = ((const float4*)x)[idx];
    float4 gm = ((const float4*)gamma)[c4];
    float4 bt = ((const float4*)beta)[c4];
    bf16x4 o;
    o[0] = (bf16)((v.x - mu) * rs * gm.x + bt.x);
    o[1] = (bf16)((v.y - mu) * rs * gm.y + bt.y);
    o[2] = (bf16)((v.z - mu) * rs * gm.z + bt.z);
    o[3] = (bf16)((v.w - mu) * rs * gm.w + bt.w);
    ((bf16x4*)xn)[idx] = o;
}

// ---------------------------------------------------------------------------
// Generalized bf16 B^T GEMM body: 128 x BN tile, BK=64, async global->LDS
// (16B), XOR-swizzled LDS (chunk ^= row&7), 16x16x32 MFMA.
//   C[m][n] = sum_k A[m][k] * Bt[n][k]
// Epilogues:
//   0: bf16 = acc + bias[n]                          (QKV proj)
//   1: bf16 = exp(acc*scale) + per-row lsum partials (QK^T + softmax-exp)
//   2: f32  = acc * (1/l[m]) + bias[n] + resid       (PV + out-proj + resid;
//        l reduced post-K-loop from lsum partials in dead As space)
//   5: bf16 = acc                                    (vpT = Wp^T v^T)
template <int EPI, int BN>
__device__ __forceinline__ void gemm2_body(
    char* smem, int bxi, int byi, int zb,
    const bf16* __restrict__ A, long long aBatch, int lda,
    const bf16* __restrict__ Bt, long long bBatch, int ldb,
    void* __restrict__ Cout, long long cBatch, int ldc,
    int K, float scale,
    const float* __restrict__ bias, const float* __restrict__ resid,
    float* __restrict__ lsum, long long lsumBatch) {
    constexpr int JN = BN / 32;
    bf16* As = (bf16*)smem;                       // 16384 B
    bf16* Bs = (bf16*)(smem + 16384);             // up to 16384 B
    const int tid = threadIdx.x;
    const int lane = tid & 63;
    const int wave = tid >> 6;

    const long long m0 = (long long)bxi * 128;
    const long long n0 = (long long)byi * BN;
    const bf16* Ab = A + (long long)zb * aBatch;
    const bf16* Bb = Bt + (long long)zb * bBatch;

    const int wm = (wave & 1) * 64;
    const int wn = (wave >> 1) * (BN / 2);
    const int fm = lane & 15;
    const int q4 = lane >> 4;

    f32x4 acc[4][JN];
    #pragma unroll
    for (int i = 0; i < 4; ++i)
        #pragma unroll
        for (int j = 0; j < JN; ++j)
            acc[i][j] = (f32x4){0.f, 0.f, 0.f, 0.f};

    const int srow = tid >> 3;
    const int schunk = (tid & 7) ^ (srow & 7);

    for (int k0 = 0; k0 < K; k0 += 64) {
        const int kk = k0 + schunk * 8;
        #pragma unroll
        for (int cb = 0; cb < 4; ++cb) {
            const bf16* g = Ab + (m0 + cb * 32 + srow) * (long long)lda + kk;
            __builtin_amdgcn_global_load_lds((const __attribute__((address_space(1))) void*)g,
                                             (__attribute__((address_space(3))) void*)&As[cb * 2048 + tid * 8], 16, 0, 0);
        }
        #pragma unroll
        for (int cb = 0; cb < BN / 32; ++cb) {
            const bf16* g = Bb + (n0 + cb * 32 + srow) * (long long)ldb + kk;
            __builtin_amdgcn_global_load_lds((const __attribute__((address_space(1))) void*)g,
                                             (__attribute__((address_space(3))) void*)&Bs[cb * 2048 + tid * 8], 16, 0, 0);
        }
        __syncthreads();
        #pragma unroll
        for (int kcc = 0; kcc < 2; ++kcc) {
            bf16x8 fa[4], fb[JN];
            #pragma unroll
            for (int i = 0; i < 4; ++i) {
                const int row = wm + i * 16 + fm;
                const int sw = ((kcc * 4 + q4) ^ (fm & 7)) * 8;
                fa[i] = *(const bf16x8*)&As[row * 64 + sw];
            }
            #pragma unroll
            for (int j = 0; j < JN; ++j) {
                const int row = wn + j * 16 + fm;
                const int sw = ((kcc * 4 + q4) ^ (fm & 7)) * 8;
                fb[j] = *(const bf16x8*)&Bs[row * 64 + sw];
            }
            #pragma unroll
            for (int i = 0; i < 4; ++i)
                #pragma unroll
                for (int j = 0; j < JN; ++j)
                    acc[i][j] = __builtin_amdgcn_mfma_f32_16x16x32_bf16(fa[i], fb[j], acc[i][j], 0, 0, 0);
        }
        __syncthreads();
    }

    // EPI 2: reduce 64 lsum partials -> lrow = 1/l, in the now-dead As space.
    float* lrow = (float*)(smem + 1024);
    if constexpr (EPI == 2) {
        float* lscr = (float*)smem;               // 1024 B
        const float* lsb = lsum + (long long)zb * lsumBatch + m0;
        const int row = tid & 127, h = tid >> 7;
        float s = 0.f;
        #pragma unroll
        for (int p = 0; p < 32; ++p)
            s += lsb[(long long)(h * 32 + p) * SEQ + row];
        lscr[tid] = s;
        __syncthreads();
        if (tid < 128) lrow[tid] = 1.f / (lscr[tid] + lscr[tid + 128]);
        __syncthreads();
    }

    // C/D layout: col = lane&15, row = (lane>>4)*4 + reg  [verified m89/m91]
    const int col = lane & 15;
    const int rowb = (lane >> 4) * 4;

    if constexpr (EPI == 1) {
        bf16* Pb = (bf16*)Cout + (long long)zb * cBatch;
        float* lsw = lsum + (long long)zb * lsumBatch
                   + ((long long)byi * 2 + (wave >> 1)) * SEQ;
        #pragma unroll
        for (int i = 0; i < 4; ++i) {
            float rs[4] = {0.f, 0.f, 0.f, 0.f};
            long long mg = m0 + wm + i * 16 + rowb;
            #pragma unroll
            for (int j = 0; j < JN; ++j) {
                long long ng = n0 + wn + j * 16 + col;
                #pragma unroll
                for (int r = 0; r < 4; ++r) {
                    float e = __expf(acc[i][j][r] * scale);
                    rs[r] += e;
                    Pb[(mg + r) * (long long)ldc + ng] = (bf16)e;
                }
            }
            #pragma unroll
            for (int r = 0; r < 4; ++r) {
                rs[r] += __shfl_xor(rs[r], 1);
                rs[r] += __shfl_xor(rs[r], 2);
                rs[r] += __shfl_xor(rs[r], 4);
                rs[r] += __shfl_xor(rs[r], 8);
            }
            if (col == 0) {
                #pragma unroll
                for (int r = 0; r < 4; ++r) lsw[mg + r] = rs[r];
            }
        }
    } else {
        #pragma unroll
        for (int i = 0; i < 4; ++i) {
            #pragma unroll
            for (int j = 0; j < JN; ++j) {
                long long mg = m0 + wm + i * 16 + rowb;
                long long ng = n0 + wn + j * 16 + col;
                #pragma unroll
                for (int r = 0; r < 4; ++r) {
                    float v = acc[i][j][r];
                    long long m = mg + r;
                    long long cidx = (long long)zb * cBatch + m * (long long)ldc + ng;
                    if constexpr (EPI == 0) {
                        ((bf16*)Cout)[cidx] = (bf16)(v + bias[ng]);
                    } else if constexpr (EPI == 2) {
                        float inv = lrow[(int)(m - m0)];
                        ((float*)Cout)[cidx] = v * inv + bias[ng] + resid[cidx];
                    } else {  // EPI == 5
                        ((bf16*)Cout)[cidx] = (bf16)v;
                    }
                }
            }
        }
    }
}

// ---------------------------------------------------------------------------
// Node 3: qkv = xn @ WqkvT^T + bias (M=8192, N=1536, K=512)
__global__ __launch_bounds__(256, 2) void k_qkv(
    const bf16* xn, const bf16* WqkvT, const float* biasQKV, bf16* qkv) {
    __shared__ __align__(16) char smem[SMEM_BYTES];
    gemm2_body<0, 128>(smem, blockIdx.x, blockIdx.y, 0,
                       xn, 0, CCH, WqkvT, 0, CCH, qkv, 0, 1536,
                       CCH, 1.f, biasQKV, nullptr, nullptr, 0);
}

// Node 4: fused QK^T+exp (nQK tile-units, first) + vpT GEMM (rest).
//   QK:  P[b] = exp(scale * q k^T), lsum partials. q/k rows of qkv.
//   vpT: vpT[b][n][j] = sum_c WpT[n][c] * v[b][j][c]  (A=WpT, Bt=v rows)
__global__ __launch_bounds__(256, 2) void k_qk_vpt(
    const bf16* qkv, const bf16* WpT, bf16* vpT, bf16* P, float* lsum,
    float scale, int nQK, long long qkBatch, long long pBatch,
    long long lsumBatch, long long vptBatch) {
    __shared__ __align__(16) char smem[SMEM_BYTES];
    const int u = blockIdx.x;
    if (u < nQK) {
        int bz = u >> 10, r = u & 1023;
        gemm2_body<1, 128>(smem, r >> 5, r & 31, bz,
                           qkv, qkBatch, 1536, qkv + 512, qkBatch, 1536,
                           P, pBatch, SEQ, CCH, scale,
                           nullptr, nullptr, lsum, lsumBatch);
    } else {
        int w = u - nQK;
        int bz = w >> 7, rr = w & 127;
        gemm2_body<5, 128>(smem, rr >> 5, rr & 31, bz,
                           WpT, 0, CCH, qkv + 1024, qkBatch, 1536,
                           vpT, vptBatch, SEQ, CCH, 1.f,
                           nullptr, nullptr, nullptr, 0);
    }
}

// Node 5: out = P/l @ vpT^T + bp + x (fp32). M=4096/batch, N=512, K=4096.
__global__ __launch_bounds__(256, 2) void k_pv(
    const bf16* P, long long pBatch, const bf16* vpT, long long vptBatch,
    const float* bp, const float* x, float* out, long long oBatch,
    float* lsum, long long lsumBatch) {
    __shared__ __align__(16) char smem[SMEM_BYTES];
    gemm2_body<2, 64>(smem, blockIdx.x, blockIdx.y, blockIdx.z,
                      P, pBatch, SEQ, vpT, vptBatch, SEQ,
                      out, oBatch, CCH, SEQ, 1.f, bp, x, lsum, lsumBatch);
}

// ---------------------------------------------------------------------------
extern "C" void kernel_launch(void* const* d_in, const int* in_sizes, int n_in,
                              void* d_out, int out_size, void* d_ws, size_t ws_size,
                              hipStream_t stream) {
    const float* x     = (const float*)d_in[0];
    const float* gamma = (const float*)d_in[1];
    const float* beta  = (const float*)d_in[2];
    const float* Wq    = (const float*)d_in[3];
    const float* bq    = (const float*)d_in[4];
    const float* Wk    = (const float*)d_in[5];
    const float* bk    = (const float*)d_in[6];
    const float* Wv    = (const float*)d_in[7];
    const float* bv    = (const float*)d_in[8];
    const float* Wp    = (const float*)d_in[9];
    const float* bp    = (const float*)d_in[10];
    float* out = (float*)d_out;

    // Workspace (aliased; lifetimes: xn dead after QKV -> lsum)
    constexpr size_t OFF_STATS = 0;          // 4 KB (statsP partials)
    constexpr size_t OFF_BIAS  = 4096;       // 6 KB
    constexpr size_t OFF_WQKVT = 12288;      // 1.57 MB
    constexpr size_t OFF_WPT   = 1585152;    // 0.5 MB [512][512]
    constexpr size_t OFF_XN    = 2109440;    // 8.39 MB; dead after QKV ->
    constexpr size_t OFF_LSUM  = OFF_XN;     //   2.10 MB [2][64][4096] f32
    constexpr size_t OFF_QKV   = 10498048;   // 25.17 MB [8192][1536] bf16
    constexpr size_t OFF_VPT   = 35663872;   // 8.39 MB vpT [2][512][4096] bf16
    constexpr size_t OFF_P     = 44052480;   // 67.1 MB (full) / 33.6 MB (per-b)
    constexpr size_t NEED_FULL = OFF_P + (size_t)NBAT * SEQ * SEQ * 2;

    char* ws = (char*)d_ws;
    float* statsP  = (float*)(ws + OFF_STATS);
    float* biasQKV = (float*)(ws + OFF_BIAS);
    bf16*  WqkvT   = (bf16*)(ws + OFF_WQKVT);
    bf16*  WpT     = (bf16*)(ws + OFF_WPT);
    bf16*  xn      = (bf16*)(ws + OFF_XN);
    float* lsum    = (float*)(ws + OFF_LSUM);
    bf16*  qkv     = (bf16*)(ws + OFF_QKV);
    bf16*  vpT     = (bf16*)(ws + OFF_VPT);
    bf16*  P       = (bf16*)(ws + OFF_P);

    const float scale = 0.044194173824159216f;  // 1/sqrt(512)
    const bool full = ws_size >= NEED_FULL;

    // 1. GN stats partials + weight transposes + bias pack
    k_prep<<<1537, 256, 0, stream>>>(x, Wq, Wk, Wv, Wp, bq, bk, bv,
                                     statsP, WqkvT, WpT, biasQKV);
    // 2. normalize + cast
    k_gn<<<4096, 256, 0, stream>>>(x, statsP, gamma, beta, xn);
    // 3. qkv projection (768 tiles)
    k_qkv<<<dim3(64, 12), 256, 0, stream>>>(xn, WqkvT, biasQKV, qkv);

    if (full) {
        // 4. QK+exp (2048 tiles) + vpT (256 tiles), both batches
        k_qk_vpt<<<2304, 256, 0, stream>>>(
            qkv, WpT, vpT, P, lsum, scale, 2048,
            (long long)SEQ * 1536, (long long)SEQ * SEQ, 64LL * SEQ,
            (long long)CCH * SEQ);
        // 5. out = P/l @ vpT^T + bp + x (512 tiles)
        k_pv<<<dim3(32, 8, NBAT), 256, 0, stream>>>(
            P, (long long)SEQ * SEQ, vpT, (long long)CCH * SEQ,
            bp, x, out, (long long)SEQ * CCH, lsum, 64LL * SEQ);
    } else {
        for (int b = 0; b < NBAT; ++b) {
            const bf16* qkvb = qkv + (long long)b * SEQ * 1536;
            bf16* vptb = vpT + (long long)b * CCH * SEQ;
            float* lsumb = lsum + (long long)b * 64 * SEQ;
            k_qk_vpt<<<1152, 256, 0, stream>>>(
                qkvb, WpT, vptb, P, lsumb, scale, 1024, 0, 0, 0, 0);
            k_pv<<<dim3(32, 8, 1), 256, 0, stream>>>(
                P, 0, vptb, 0, bp, x + (long long)b * SEQ * CCH,
                out + (long long)b * SEQ * CCH, 0, lsumb, 0);
        }
    }
}